// Round 8
// baseline (40013.577 us; speedup 1.0000x reference)
//
#include <hip/hip_runtime.h>
#include <math.h>

// ============================================================================
// KNet RNN — persistent kernel, round 8: de-hotspot + traffic cuts.
//  - E epilogue: LDS tile + cooperative coalesced hid2 write (was 288K
//    scattered scalar sc stores/step = 16 MB/step write-allocate traffic)
//  - F: 15 j x 15 k-chunk WGs; hid2 re-read 57x -> 15x; partials via relaxed
//    agent float atomicAdd into out2 (seeded b2b in E); G reads out2 directly
//  - broadcast vectors replicated x4 (readers pick bx&3); barrier GO flag
//    replicated x16 lines (was: 225-256 readers serializing on one LLC line)
//  - fence-free coherence model from round 6 retained
// ============================================================================

#define NWG 256
#define NTH 1024
#define TT  256
#define NEPOCH 1792            // 7 * 256
#define EP_STRIDE 272          // 16 group lines (16 ints) + 1 top line
#define OFF_GO   (NEPOCH*EP_STRIDE)
#define INT_TOTAL (OFF_GO + 256)   // 16 GO replica lines

// float-region offsets (all multiples of 4)
#define F_HQ    0         // [2][4][3648]  phase, replica
#define F_HS    29184     // [2][4][3648]
#define F_HSIG  58368     // [4][3648]
#define F_OSIG  72960     // [4][3648]
#define F_OUT1  87552     // [4][3648]
#define F_OUT3  102144    // [4][3648]
#define F_XV    116736    // [4][7232]
#define F_OUT2  145664    // [16][228]
#define F_XP    149312    // [240]
#define F_DY    149568    // [4][256]
#define F_FWD   150592    // [4][256]
#define F_OBSD  151616    // [4][256]
#define F_HID2  152640    // [16][18000]
#define PQ      440640    // 675 x 304
#define PSIG    645840    // 675 x 544
#define PS      1013040   // 675 x 608
#define PW1     1423440   // 225 x 228
#define PW3     1474740   // 225 x 456
#define PW4     1577340   // 225 x 456
#define PW5     1679940   // 75 x 16
#define PW6     1681140   // 75 x 16
#define PW7     1682340   // 150 x 32
#define W2AP    1687140   // 18000 x 452

#define PH 14592          // phase stride for HQ/HS

// LDS layout (floats)
#define L_OUT5 0
#define L_OUT6 1216
#define L_OUT7 2432
#define L_OUT2 4864       // G: ..8511
#define L_XV   0          // E: ..7231
#define L_HT   7232       // E: [16][72] ..8383
#define L_SCR  8512       // ..9023
#define L_TOTAL 9024

typedef float v4f __attribute__((ext_vector_type(4)));

struct KArgs {
  const float *y,*x0,*hQ0,*hSig0,*hS0;
  const float *WihQ,*WhhQ,*bihQ,*bhhQ;
  const float *WihSig,*WhhSig,*bihSig,*bhhSig;
  const float *WihS,*WhhS,*bihS,*bhhS;
  const float *W1,*b1,*W2a,*b2a,*W2b,*b2b,*W3,*b3,*W4,*b4;
  const float *W5,*b5,*W6,*b6,*W7,*b7;
  float* out;
  int*   ib;
  float* fb;
};

__device__ __forceinline__ float sigf(float x) { return 1.0f/(1.0f + __expf(-x)); }
__device__ __forceinline__ float dp4(float acc, float4 w, float4 x) {
  acc = fmaf(w.x, x.x, acc); acc = fmaf(w.y, x.y, acc);
  acc = fmaf(w.z, x.z, acc); acc = fmaf(w.w, x.w, acc);
  return acc;
}
__device__ __forceinline__ float4 ldg4(const float* p){ return *(const float4*)p; }
__device__ __forceinline__ float4 ldg4nt(const float* p){
  v4f r = __builtin_nontemporal_load((const v4f*)p);
  float4 o; o.x = r.x; o.y = r.y; o.z = r.z; o.w = r.w; return o;
}

// coherent (sc-bypass) accessors for cross-WG communicated data
__device__ __forceinline__ float ald(const float* p) {
  return __hip_atomic_load(p, __ATOMIC_RELAXED, __HIP_MEMORY_SCOPE_AGENT);
}
__device__ __forceinline__ float4 ald4(const float* p) {
  float4 r; r.x=ald(p); r.y=ald(p+1); r.z=ald(p+2); r.w=ald(p+3); return r;
}
__device__ __forceinline__ void ast(float* p, float v) {
  __hip_atomic_store(p, v, __ATOMIC_RELAXED, __HIP_MEMORY_SCOPE_AGENT);
}
__device__ __forceinline__ void ast4(float* p, float v) {   // 4 replicas
  ast(p, v); ast(p + 3648, v); ast(p + 2*3648, v); ast(p + 3*3648, v);
}
__device__ __forceinline__ void aadd(float* p, float v) {
  __hip_atomic_fetch_add(p, v, __ATOMIC_RELAXED, __HIP_MEMORY_SCOPE_AGENT);
}

__device__ __forceinline__ float red64(float v) {
  v += __shfl_xor(v, 1, 64);  v += __shfl_xor(v, 2, 64);
  v += __shfl_xor(v, 4, 64);  v += __shfl_xor(v, 8, 64);
  v += __shfl_xor(v, 16, 64); v += __shfl_xor(v, 32, 64);
  return v;
}

// Fence-free barrier, GO flag replicated over 16 cache lines.
__device__ __forceinline__ void gbar(int* ib, int e) {
  __builtin_amdgcn_s_waitcnt(0);
  __syncthreads();
  if (threadIdx.x == 0) {
    const int base = e * EP_STRIDE;
    const int g = (int)(blockIdx.x >> 4);
    int prev = __hip_atomic_fetch_add(ib + base + g*16, 1,
                                      __ATOMIC_RELAXED, __HIP_MEMORY_SCOPE_AGENT);
    if (prev == 15) {
      int pt = __hip_atomic_fetch_add(ib + base + 256, 1,
                                      __ATOMIC_RELAXED, __HIP_MEMORY_SCOPE_AGENT);
      if (pt == 15) {
        #pragma unroll
        for (int r = 0; r < 16; ++r)
          __hip_atomic_store(ib + OFF_GO + r*16, e, __ATOMIC_RELAXED, __HIP_MEMORY_SCOPE_AGENT);
      }
    }
    int* go = ib + OFF_GO + ((int)blockIdx.x & 15)*16;
    while (__hip_atomic_load(go, __ATOMIC_RELAXED, __HIP_MEMORY_SCOPE_AGENT) < e)
      __builtin_amdgcn_s_sleep(2);
  }
  __syncthreads();
}

__global__ void knet_init(KArgs a) {
  int gt = blockIdx.x*blockDim.x + threadIdx.x;
  int nt = gridDim.x*blockDim.x;
  float* F = a.fb;
  for (int i = gt; i < INT_TOTAL; i += nt)
    a.ib[i] = (i >= OFF_GO && ((i - OFF_GO) & 15) == 0) ? -1 : 0;
  for (int i = gt; i < 14592; i += nt) {           // 4 replicas, phase 0
    int idx = i % 3648;
    int b = idx/228, j = idx - b*228;
    float hq=0.f, hs=0.f, hg=0.f;
    if (j < 225) { hq = a.hQ0[b*225+j]; hs = a.hS0[b*225+j]; hg = a.hSig0[b*225+j]; }
    F[F_HQ + i] = hq; F[F_HS + i] = hs; F[F_HSIG + i] = hg;
  }
  for (int i = gt; i < 4*7232; i += nt) F[F_XV + i] = 0.f;
  for (int i = gt; i < 240; i += nt) F[F_XP + i] = a.x0[i];
  for (int i = gt; i < 1024; i += nt) {            // 4 replicas of [16][16]
    int idx = i & 255;
    int b = idx >> 4, j = idx & 15;
    float dy=0.f, od=0.f;
    if (j < 15) {
      float ob = a.y[b*30 + j], xv = a.x0[b*15 + j];
      dy = ob - xv; od = ob - xv;
    }
    F[F_DY + i] = dy; F[F_OBSD + i] = od; F[F_FWD + i] = 0.f;
  }
  for (int i = gt; i < 675*304; i += nt) {
    int r = i/304, d = i - r*304; float v = 0.f;
    if (d < 75) v = a.WihQ[r*75 + d];
    else if (d >= 76 && d < 301) v = a.WhhQ[r*225 + d - 76];
    F[PQ + i] = v;
  }
  for (int i = gt; i < 675*544; i += nt) {
    int r = i/544, d = i - r*544; float v = 0.f;
    if (d < 225) v = a.WihSig[r*300 + d];
    else if (d >= 228 && d < 303) v = a.WihSig[r*300 + 225 + d - 228];
    else if (d >= 304 && d < 529) v = a.WhhSig[r*225 + d - 304];
    F[PSIG + i] = v;
  }
  for (int i = gt; i < 675*608; i += nt) {
    int r = i/608, d = i - r*608; float v = 0.f;
    if (d < 225) v = a.WihS[r*375 + d];
    else if (d >= 228 && d < 378) v = a.WihS[r*375 + 225 + d - 228];
    else if (d >= 380 && d < 605) v = a.WhhS[r*225 + d - 380];
    F[PS + i] = v;
  }
  for (int i = gt; i < 225*228; i += nt) {
    int r = i/228, d = i - r*228;
    F[PW1 + i] = (d < 225) ? a.W1[r*225 + d] : 0.f;
  }
  for (int i = gt; i < 225*456; i += nt) {
    int r = i/456, d = i - r*456; float v3 = 0.f, v4 = 0.f;
    if (d < 225)               { v3 = a.W3[r*450 + d];           v4 = a.W4[r*450 + d]; }
    else if (d >= 228 && d < 453) { v3 = a.W3[r*450 + 225 + d - 228]; v4 = a.W4[r*450 + 225 + d - 228]; }
    F[PW3 + i] = v3; F[PW4 + i] = v4;
  }
  for (int i = gt; i < 75*16; i += nt) {
    int r = i >> 4, d = i & 15;
    F[PW5 + i] = (d < 15) ? a.W5[r*15 + d] : 0.f;
    F[PW6 + i] = (d < 15) ? a.W6[r*15 + d] : 0.f;
  }
  for (int i = gt; i < 150*32; i += nt) {
    int r = i >> 5, d = i & 31; float v = 0.f;
    if (d < 15) v = a.W7[r*30 + d];
    else if (d >= 16 && d < 31) v = a.W7[r*30 + 15 + d - 16];
    F[PW7 + i] = v;
  }
  for (long long i = gt; i < 18000LL*452; i += nt) {
    long long r = i/452; int d = (int)(i - r*452);
    F[W2AP + i] = (d < 450) ? a.W2a[r*450 + d] : 0.f;
  }
}

__global__ __launch_bounds__(NTH, 4) void knet_main(KArgs a) {
  __shared__ float smem[L_TOTAL];
  const int tid  = threadIdx.x;
  const int widx = tid >> 6;
  const int l    = tid & 63;
  const int bx   = (int)blockIdx.x;
  const int k0   = l*4;
  const int rep  = bx & 3;
  float* F  = a.fb;
  int*   ib = a.ib;
  int ep = 0;

  for (int t = 0; t < TT; ++t) {
    const int p = t & 1, q = p ^ 1;
    float* hQi = F + F_HQ + p*PH + rep*3648;   // read replica
    float* hQo = F + F_HQ + q*PH;              // write base (all 4)
    float* hSi = F + F_HS + p*PH + rep*3648;
    float* hSo = F + F_HS + q*PH;
    float* hSoR = F + F_HS + q*PH + rep*3648;  // read replica of this step's hS

    // ==== A: out5(LDS) ; hQ GRU ; hSig = out4(prev osig,out3) ==============
    if (bx < 225) {
      if (tid < 256) smem[L_SCR + tid] = ald(F + F_FWD + rep*256 + tid);
      __syncthreads();
      for (int i = tid; i < 1200; i += NTH) {
        int bb = i/75, j5 = i - bb*75;
        const float4* w  = (const float4*)(F + PW5 + j5*16);
        const float4* xv = (const float4*)(smem + L_SCR + bb*16);
        float acc = a.b5[j5];
        acc = dp4(acc, w[0], xv[0]); acc = dp4(acc, w[1], xv[1]);
        acc = dp4(acc, w[2], xv[2]); acc = dp4(acc, w[3], xv[3]);
        smem[L_OUT5 + bb*76 + j5] = fmaxf(acc, 0.f);
      }
      __syncthreads();
      const int j = bx, bw = widx;
      float4 xq0 = (k0 < 76) ? *(const float4*)(smem + L_OUT5 + bw*76 + k0)
                             : ald4(hQi + bw*228 + k0 - 76);
      float4 xq1; if (l < 12) xq1 = ald4(hQi + bw*228 + 180 + k0);
      float4 xw0 = (l < 57) ? ald4(F + F_OSIG + rep*3648 + bw*228 + k0)
                            : ald4(F + F_OUT3 + rep*3648 + bw*228 + k0 - 228);
      float4 xw1; if (l < 50) xw1 = ald4(F + F_OUT3 + rep*3648 + bw*228 + 28 + k0);
      const float* qr = F + PQ + (size_t)j*304;
      const float* qz = qr + 225*304;
      const float* qn = qr + 450*304;
      const float* w4r = F + PW4 + (size_t)j*456;
      float4 wr0 = ldg4(qr + k0), wz0 = ldg4(qz + k0), wn0 = ldg4(qn + k0);
      float4 w40 = ldg4(w4r + k0);
      float ar=0.f, az=0.f, ani=0.f, anh=0.f, a4=0.f;
      ar = dp4(ar, wr0, xq0); az = dp4(az, wz0, xq0);
      { float tt = dp4(0.f, wn0, xq0); if (k0 < 76) ani += tt; else anh += tt; }
      a4 = dp4(a4, w40, xw0);
      if (l < 12) {
        float4 wr1 = ldg4(qr + 256 + k0), wz1 = ldg4(qz + 256 + k0), wn1 = ldg4(qn + 256 + k0);
        ar = dp4(ar, wr1, xq1); az = dp4(az, wz1, xq1); anh = dp4(anh, wn1, xq1);
      }
      if (l < 50) a4 = dp4(a4, ldg4(w4r + 256 + k0), xw1);
      ar = red64(ar); az = red64(az); ani = red64(ani); anh = red64(anh); a4 = red64(a4);
      if (l == 0) {
        float r = sigf(ar + a.bihQ[j] + a.bhhQ[j]);
        float z = sigf(az + a.bihQ[225+j] + a.bhhQ[225+j]);
        float n = tanhf(ani + a.bihQ[450+j] + r*(anh + a.bhhQ[450+j]));
        ast4(&hQo[bw*228 + j], (1.f - z)*n + z*ald(&hQi[bw*228 + j]));
        if (t > 0) ast4(&F[F_HSIG + bw*228 + j], fmaxf(a4 + a.b4[j], 0.f));
      }
    }
    gbar(ib, ep); ++ep;

    // ==== B: out6(LDS) ; osig GRU (x=[hQ|out6], h=hSig) ====================
    if (bx < 225) {
      for (int i = tid; i < 1200; i += NTH) {
        int bb = i/75, j6 = i - bb*75;
        const float4* w  = (const float4*)(F + PW6 + j6*16);
        const float4* xv = (const float4*)(smem + L_SCR + bb*16);   // FWD persists
        float acc = a.b6[j6];
        acc = dp4(acc, w[0], xv[0]); acc = dp4(acc, w[1], xv[1]);
        acc = dp4(acc, w[2], xv[2]); acc = dp4(acc, w[3], xv[3]);
        smem[L_OUT6 + bb*76 + j6] = fmaxf(acc, 0.f);
      }
      __syncthreads();
      const int j = bx, bw = widx;
      const float* hsg = F + F_HSIG + rep*3648;
      float4 x0 = (l < 57) ? ald4(F + F_HQ + q*PH + rep*3648 + bw*228 + k0)
                           : *(const float4*)(smem + L_OUT6 + bw*76 + k0 - 228);
      float4 x1 = (l < 12) ? *(const float4*)(smem + L_OUT6 + bw*76 + 28 + k0)
                           : ald4(hsg + bw*228 + k0 - 48);
      float4 x2; if (l < 5) x2 = ald4(hsg + bw*228 + 208 + k0);
      const float* gr = F + PSIG + (size_t)j*544;
      const float* gz = gr + 225*544;
      const float* gn = gr + 450*544;
      float4 wr0 = ldg4(gr + k0),     wz0 = ldg4(gz + k0),     wn0 = ldg4(gn + k0);
      float4 wr1 = ldg4(gr + 256+k0), wz1 = ldg4(gz + 256+k0), wn1 = ldg4(gn + 256+k0);
      float ar=0.f, az=0.f, ani=0.f, anh=0.f;
      ar = dp4(ar, wr0, x0); az = dp4(az, wz0, x0); ani = dp4(ani, wn0, x0);
      ar = dp4(ar, wr1, x1); az = dp4(az, wz1, x1);
      { float tt = dp4(0.f, wn1, x1); if (l < 12) ani += tt; else anh += tt; }
      if (l < 5) {
        float4 wr2 = ldg4(gr + 512+k0), wz2 = ldg4(gz + 512+k0), wn2 = ldg4(gn + 512+k0);
        ar = dp4(ar, wr2, x2); az = dp4(az, wz2, x2); anh = dp4(anh, wn2, x2);
      }
      ar = red64(ar); az = red64(az); ani = red64(ani); anh = red64(anh);
      if (l == 0) {
        float r = sigf(ar + a.bihSig[j] + a.bhhSig[j]);
        float z = sigf(az + a.bihSig[225+j] + a.bhhSig[225+j]);
        float n = tanhf(ani + a.bihSig[450+j] + r*(anh + a.bhhSig[450+j]));
        float val = (1.f - z)*n + z*ald(&F[F_HSIG + rep*3648 + bw*228 + j]);
        ast4(&F[F_OSIG + bw*228 + j], val);
        float* xvp = F + F_XV + bw*452 + j;
        ast(xvp, val); ast(xvp+7232, val); ast(xvp+2*7232, val); ast(xvp+3*7232, val);
      }
    }
    gbar(ib, ep); ++ep;

    // ==== C: out1 = relu(W1 @ osig + b1) ===================================
    if (bx < 225) {
      const int j = bx, bw = widx;
      float acc = 0.f;
      if (l < 57) {
        float4 w0 = ldg4(F + PW1 + (size_t)j*228 + k0);
        float4 x0 = ald4(F + F_OSIG + rep*3648 + bw*228 + k0);
        acc = dp4(0.f, w0, x0);
      }
      acc = red64(acc);
      if (l == 0) ast4(&F[F_OUT1 + bw*228 + j], fmaxf(acc + a.b1[j], 0.f));
    }
    gbar(ib, ep); ++ep;

    // ==== D: out7(LDS) ; hS GRU (x=[out1|out7], h=hS) ======================
    if (bx < 225) {
      if (tid < 256)      smem[L_SCR + tid]       = ald(F + F_OBSD + rep*256 + tid);
      else if (tid < 512) smem[L_SCR + tid]       = ald(F + F_DY + rep*256 + tid - 256);
      __syncthreads();
      for (int i = tid; i < 2400; i += NTH) {
        int bb = i/150, j7 = i - bb*150;
        const float4* w  = (const float4*)(F + PW7 + j7*32);
        const float4* vo = (const float4*)(smem + L_SCR + bb*16);
        const float4* vd = (const float4*)(smem + L_SCR + 256 + bb*16);
        float acc = a.b7[j7];
        acc = dp4(acc, w[0], vo[0]); acc = dp4(acc, w[1], vo[1]);
        acc = dp4(acc, w[2], vo[2]); acc = dp4(acc, w[3], vo[3]);
        acc = dp4(acc, w[4], vd[0]); acc = dp4(acc, w[5], vd[1]);
        acc = dp4(acc, w[6], vd[2]); acc = dp4(acc, w[7], vd[3]);
        smem[L_OUT7 + bb*152 + j7] = fmaxf(acc, 0.f);
      }
      __syncthreads();
      const int j = bx, bw = widx;
      float4 x0 = (l < 57) ? ald4(F + F_OUT1 + rep*3648 + bw*228 + k0)
                           : *(const float4*)(smem + L_OUT7 + bw*152 + k0 - 228);
      float4 x1 = (l < 31) ? *(const float4*)(smem + L_OUT7 + bw*152 + 28 + k0)
                           : ald4(hSi + bw*228 + k0 - 124);
      float4 x2; if (l < 24) x2 = ald4(hSi + bw*228 + 132 + k0);
      const float* gr = F + PS + (size_t)j*608;
      const float* gz = gr + 225*608;
      const float* gn = gr + 450*608;
      float4 wr0 = ldg4(gr + k0),     wz0 = ldg4(gz + k0),     wn0 = ldg4(gn + k0);
      float4 wr1 = ldg4(gr + 256+k0), wz1 = ldg4(gz + 256+k0), wn1 = ldg4(gn + 256+k0);
      float ar=0.f, az=0.f, ani=0.f, anh=0.f;
      ar = dp4(ar, wr0, x0); az = dp4(az, wz0, x0); ani = dp4(ani, wn0, x0);
      ar = dp4(ar, wr1, x1); az = dp4(az, wz1, x1);
      { float tt = dp4(0.f, wn1, x1); if (l < 31) ani += tt; else anh += tt; }
      if (l < 24) {
        float4 wr2 = ldg4(gr + 512+k0), wz2 = ldg4(gz + 512+k0), wn2 = ldg4(gn + 512+k0);
        ar = dp4(ar, wr2, x2); az = dp4(az, wz2, x2); anh = dp4(anh, wn2, x2);
      }
      ar = red64(ar); az = red64(az); ani = red64(ani); anh = red64(anh);
      if (l == 0) {
        float r = sigf(ar + a.bihS[j] + a.bhhS[j]);
        float z = sigf(az + a.bihS[225+j] + a.bhhS[225+j]);
        float n = tanhf(ani + a.bihS[450+j] + r*(anh + a.bhhS[450+j]));
        float val = (1.f - z)*n + z*ald(&hSi[bw*228 + j]);
        ast4(&hSo[bw*228 + j], val);
        float* xvp = F + F_XV + bw*452 + 225 + j;
        ast(xvp, val); ast(xvp+7232, val); ast(xvp+2*7232, val); ast(xvp+3*7232, val);
      }
    }
    gbar(ib, ep); ++ep;

    // ==== E: hid2 = relu(W2aP @ xv + b2a); LDS tile -> coalesced write =====
    if (bx < 250) {
      const float* xvsrc = F + F_XV + rep*7232;
      for (int i = tid; i < 7232; i += NTH) smem[L_XV + i] = ald(xvsrc + i);
      __syncthreads();
      const int r0 = bx*72;
      for (int ps = 0; ps < 3; ++ps) {
        const int pi = ps*16 + widx;
        if (pi >= 36) break;
        const int rA = r0 + 2*pi;
        const float* wAp = F + W2AP + (size_t)rA*452;
        const float* wBp = wAp + 452;
        float aA[16], aB[16];
        #pragma unroll
        for (int i = 0; i < 16; ++i) { aA[i] = 0.f; aB[i] = 0.f; }
        {
          float4 wA = ldg4(wAp + k0), wB = ldg4(wBp + k0);
          #pragma unroll
          for (int bb = 0; bb < 16; ++bb) {
            float4 xv = *(const float4*)(smem + L_XV + bb*452 + k0);
            aA[bb] = dp4(aA[bb], wA, xv);
            aB[bb] = dp4(aB[bb], wB, xv);
          }
        }
        if (l < 49) {
          float4 wA = ldg4(wAp + 256 + k0), wB = ldg4(wBp + 256 + k0);
          #pragma unroll
          for (int bb = 0; bb < 16; ++bb) {
            float4 xv = *(const float4*)(smem + L_XV + bb*452 + 256 + k0);
            aA[bb] = dp4(aA[bb], wA, xv);
            aB[bb] = dp4(aB[bb], wB, xv);
          }
        }
        #pragma unroll
        for (int i = 0; i < 16; ++i) { aA[i] = red64(aA[i]); aB[i] = red64(aB[i]); }
        if (l == 0) {
          float bA = a.b2a[rA], bB = a.b2a[rA + 1];
          #pragma unroll
          for (int i = 0; i < 16; ++i) {
            smem[L_HT + i*72 + 2*pi]     = fmaxf(aA[i] + bA, 0.f);
            smem[L_HT + i*72 + 2*pi + 1] = fmaxf(aB[i] + bB, 0.f);
          }
        }
      }
      __syncthreads();
      for (int i = tid; i < 1152; i += NTH) {
        int b2 = i/72, rl = i - b2*72;
        ast(&F[F_HID2 + b2*18000 + r0 + rl], smem[L_HT + i]);
      }
    } else if (bx == 250) {            // seed out2 = b2b
      for (int i = tid; i < 3648; i += NTH) {
        int j2 = i % 228;
        ast(&F[F_OUT2 + i], (j2 < 225) ? a.b2b[j2] : 0.f);
      }
    }
    gbar(ib, ep); ++ep;

    // ==== F: out2 += W2b-chunk @ hid2-chunk; 15 j x 15 kq WGs, atomics =====
    if (bx < 225) {
      const int jg = bx/15, kq = bx - jg*15;
      const int j0 = jg*15, b = widx;
      const float* hb = F + F_HID2 + (size_t)b*18000 + kq*1200;
      float4 h4[5];
      #pragma unroll
      for (int u = 0; u < 4; ++u) h4[u] = ald4(hb + (u*64 + l)*4);
      if (l < 44) h4[4] = ald4(hb + (256 + l)*4);
      float acc[15];
      #pragma unroll
      for (int jj = 0; jj < 15; ++jj) acc[jj] = 0.f;
      #pragma unroll
      for (int jj = 0; jj < 15; ++jj) {
        const float* wr = a.W2b + (size_t)(j0 + jj)*18000 + kq*1200;
        #pragma unroll
        for (int u = 0; u < 4; ++u)
          acc[jj] = dp4(acc[jj], ldg4nt(wr + (u*64 + l)*4), h4[u]);
        if (l < 44) acc[jj] = dp4(acc[jj], ldg4nt(wr + (256 + l)*4), h4[4]);
      }
      #pragma unroll
      for (int jj = 0; jj < 15; ++jj) acc[jj] = red64(acc[jj]);
      if (l == 0) {
        float* o2 = F + F_OUT2 + b*228 + j0;
        #pragma unroll
        for (int jj = 0; jj < 15; ++jj) aadd(o2 + jj, acc[jj]);
      }
    }
    gbar(ib, ep); ++ep;

    // ==== G: out2(LDS) ; out3 = relu(W3@[hS|out2]+b3) ; x update ===========
    if (bx < 225) {
      for (int i = tid; i < 3648; i += NTH) {
        int j2 = i % 228;
        smem[L_OUT2 + i] = (j2 < 225) ? ald(F + F_OUT2 + i) : 0.f;
      }
      __syncthreads();
      const int j = bx, bw = widx;
      float4 x0 = (l < 57) ? ald4(hSoR + bw*228 + k0)
                           : *(const float4*)(smem + L_OUT2 + bw*228 + k0 - 228);
      float4 x1; if (l < 50) x1 = *(const float4*)(smem + L_OUT2 + bw*228 + 28 + k0);
      const float* w3r = F + PW3 + (size_t)j*456;
      float acc = dp4(0.f, ldg4(w3r + k0), x0);
      if (l < 50) acc = dp4(acc, ldg4(w3r + 256 + k0), x1);
      acc = red64(acc);
      if (l == 0) ast4(&F[F_OUT3 + bw*228 + j], fmaxf(acc + a.b3[j], 0.f));
    } else if (bx == 225) {
      for (int i = tid; i < 240; i += NTH) {
        int bb = i/15, jj = i - bb*15;
        float o2 = ald(&F[F_OUT2 + bb*228 + jj]);
        float xold = ald(&F[F_XP + i]), dy = ald(&F[F_DY + rep*256 + bb*16 + jj]);
        float xnew = fmaf(o2, dy, xold);
        a.out[t*240 + i] = xnew;
        ast(&F[F_XP + i], xnew);
        if (t + 1 < TT) {
          float y1 = a.y[(t+1)*480 + bb*30 + jj];
          float y0 = a.y[t*480     + bb*30 + jj];
          #pragma unroll
          for (int r = 0; r < 4; ++r) {
            ast(&F[F_DY   + r*256 + bb*16 + jj], y1 - xnew);
            ast(&F[F_OBSD + r*256 + bb*16 + jj], y1 - y0);
            ast(&F[F_FWD  + r*256 + bb*16 + jj], xnew - xold);
          }
        }
      }
    }
    gbar(ib, ep); ++ep;
  }
}

extern "C" void kernel_launch(void* const* d_in, const int* in_sizes, int n_in,
                              void* d_out, int out_size, void* d_ws, size_t ws_size,
                              hipStream_t stream) {
  (void)in_sizes; (void)n_in; (void)out_size; (void)ws_size;
  KArgs a;
  int k = 0;
  a.y      = (const float*)d_in[k++];
  a.x0     = (const float*)d_in[k++];
  a.hQ0    = (const float*)d_in[k++];
  a.hSig0  = (const float*)d_in[k++];
  a.hS0    = (const float*)d_in[k++];
  a.WihQ   = (const float*)d_in[k++];
  a.WhhQ   = (const float*)d_in[k++];
  a.bihQ   = (const float*)d_in[k++];
  a.bhhQ   = (const float*)d_in[k++];
  a.WihSig = (const float*)d_in[k++];
  a.WhhSig = (const float*)d_in[k++];
  a.bihSig = (const float*)d_in[k++];
  a.bhhSig = (const float*)d_in[k++];
  a.WihS   = (const float*)d_in[k++];
  a.WhhS   = (const float*)d_in[k++];
  a.bihS   = (const float*)d_in[k++];
  a.bhhS   = (const float*)d_in[k++];
  a.W1  = (const float*)d_in[k++];  a.b1  = (const float*)d_in[k++];
  a.W2a = (const float*)d_in[k++];  a.b2a = (const float*)d_in[k++];
  a.W2b = (const float*)d_in[k++];  a.b2b = (const float*)d_in[k++];
  a.W3  = (const float*)d_in[k++];  a.b3  = (const float*)d_in[k++];
  a.W4  = (const float*)d_in[k++];  a.b4  = (const float*)d_in[k++];
  a.W5  = (const float*)d_in[k++];  a.b5  = (const float*)d_in[k++];
  a.W6  = (const float*)d_in[k++];  a.b6  = (const float*)d_in[k++];
  a.W7  = (const float*)d_in[k++];  a.b7  = (const float*)d_in[k++];
  a.out = (float*)d_out;
  a.ib  = (int*)d_ws;
  a.fb  = (float*)((char*)d_ws + (size_t)INT_TOTAL*sizeof(int));

  hipLaunchKernelGGL(knet_init, dim3(2048), dim3(256), 0, stream, a);
  hipLaunchKernelGGL(knet_main, dim3(NWG), dim3(NTH), 0, stream, a);
}